// Round 1
// baseline (877.706 us; speedup 1.0000x reference)
//
#include <hip/hip_runtime.h>
#include <hip/hip_bf16.h>
#include <math.h>

typedef float f4 __attribute__((ext_vector_type(4)));

#define B_  4096
#define F_  100
#define H_  128
#define H2_ 64
#define T_  2
#define TB  128
#define HS  132   // padded LDS row stride for activations
#define NG  8     // feature groups -> grid.y

__device__ __forceinline__ float elu1(float v) { return v > 0.f ? v : expm1f(v); }

// ---- head fold: wv[f,t,h] = sum_m Wh1[f,t,h,m]*Wh2[f,t,m]; cb[f,t] = sum_m bh1*Wh2 + bh2
__global__ void head_fold(const float* __restrict__ Wh1, const float* __restrict__ bh1,
                          const float* __restrict__ Wh2, const float* __restrict__ bh2,
                          float* __restrict__ wv, float* __restrict__ cb) {
  int bid = blockIdx.x;          // f*T + t, 0..199
  int l = threadIdx.x;           // 0..63
  __shared__ __align__(16) float w2s[H2_];
  w2s[l] = Wh2[bid * H2_ + l];
  __syncthreads();
  const float* base = Wh1 + (size_t)bid * H_ * H2_;
  for (int h = l; h < H_; h += 64) {
    float s = 0.f;
    const f4* rw = (const f4*)(base + (size_t)h * H2_);
    #pragma unroll
    for (int m4 = 0; m4 < H2_ / 4; ++m4) {
      f4 av = rw[m4];
      f4 bv = ((const f4*)w2s)[m4];
      s += av[0]*bv[0] + av[1]*bv[1] + av[2]*bv[2] + av[3]*bv[3];
    }
    wv[bid * H_ + h] = s;
  }
  float p = bh1[bid * H2_ + l] * w2s[l];
  #pragma unroll
  for (int off = 32; off > 0; off >>= 1) p += __shfl_xor(p, off);
  if (l == 0) cb[bid] = p + bh2[bid];
}

// 8x8 register-tile GEMM over LDS: acc[i][j] = sum_k sH[(ty+16i)*HS+k] * sW[k*H + c0+j]
__device__ __forceinline__ void gemm_tile(float acc[8][8], const float* sH, const float* sW,
                                          int ty, int c0) {
  #pragma unroll
  for (int i = 0; i < 8; ++i)
    #pragma unroll
    for (int j = 0; j < 8; ++j) acc[i][j] = 0.f;
  #pragma unroll 2
  for (int kc = 0; kc < H_; kc += 4) {
    f4 av[8];
    #pragma unroll
    for (int i = 0; i < 8; ++i) av[i] = *(const f4*)&sH[(ty + 16*i)*HS + kc];
    f4 w0[4], w1[4];
    #pragma unroll
    for (int j = 0; j < 4; ++j) {
      w0[j] = *(const f4*)&sW[(kc + j)*H_ + c0];
      w1[j] = *(const f4*)&sW[(kc + j)*H_ + c0 + 4];
    }
    #pragma unroll
    for (int j = 0; j < 4; ++j) {
      #pragma unroll
      for (int i = 0; i < 8; ++i) {
        float s = av[i][j];
        acc[i][0] += s * w0[j][0]; acc[i][1] += s * w0[j][1];
        acc[i][2] += s * w0[j][2]; acc[i][3] += s * w0[j][3];
        acc[i][4] += s * w1[j][0]; acc[i][5] += s * w1[j][1];
        acc[i][6] += s * w1[j][2]; acc[i][7] += s * w1[j][3];
      }
    }
  }
}

__global__ __launch_bounds__(256, 1) void nam_main(
    const float* __restrict__ x,  const int* __restrict__ a,
    const float* __restrict__ W1, const float* __restrict__ b1,
    const float* __restrict__ W2, const float* __restrict__ b2,
    const float* __restrict__ W3, const float* __restrict__ b3,
    const float* __restrict__ W4, const float* __restrict__ b4,
    const float* __restrict__ wv, const float* __restrict__ cb,
    float* __restrict__ out) {
  __shared__ __align__(16) float sW[H_ * H_];    // 64 KB weight tile
  __shared__ __align__(16) float sH[TB * HS];    // 67.6 KB activation tile
  __shared__ __align__(16) float sY[TB * 16];    // 8 KB y-reduction

  const int tid = threadIdx.x;
  const int ty = tid >> 4, tx = tid & 15;
  const int c0 = tx * 8;
  const int r0 = blockIdx.x * TB;
  const int g  = blockIdx.y;
  const int f0 = (g * F_) / NG, f1 = ((g + 1) * F_) / NG;

  int ta[8];
  #pragma unroll
  for (int i = 0; i < 8; ++i) ta[i] = a[r0 + ty + 16*i];

  float bbsum[8][8];
  #pragma unroll
  for (int i = 0; i < 8; ++i)
    #pragma unroll
    for (int j = 0; j < 8; ++j) bbsum[i][j] = 0.f;
  float ysum[8] = {0.f,0.f,0.f,0.f,0.f,0.f,0.f,0.f};
  float acc[8][8];

  for (int f = f0; f < f1; ++f) {
    __syncthreads();   // previous iteration's readers of sH/sW are done
    // ---- phase 1: W2 -> sW, h1 = elu(x*W1+b1) -> sH
    {
      const f4* gw = (const f4*)(W2 + (size_t)f * H_ * H_);
      f4* sWv = (f4*)sW;
      #pragma unroll
      for (int rr = 0; rr < 16; ++rr) sWv[tid + 256*rr] = gw[tid + 256*rr];
      const int row = tid >> 1;                      // 2 threads per row
      const float xs = x[(size_t)(r0 + row) * F_ + f];
      const f4* w1v = (const f4*)(W1 + (size_t)f * H_);
      const f4* b1v = (const f4*)(b1 + (size_t)f * H_);
      #pragma unroll
      for (int rr = 0; rr < 16; ++rr) {
        int h4 = (tid & 1) * 16 + rr;
        f4 w = w1v[h4], bv = b1v[h4], v;
        #pragma unroll
        for (int c = 0; c < 4; ++c) { float t0 = xs * w[c] + bv[c]; v[c] = elu1(t0); }
        *(f4*)&sH[row * HS + h4 * 4] = v;
      }
    }
    __syncthreads();
    // ---- GEMM1 (h1*W2 + b2, elu)
    gemm_tile(acc, sH, sW, ty, c0);
    __syncthreads();   // all reads of sH/sW done
    {
      const f4 bb0 = *(const f4*)(b2 + (size_t)f * H_ + c0);
      const f4 bb1 = *(const f4*)(b2 + (size_t)f * H_ + c0 + 4);
      #pragma unroll
      for (int i = 0; i < 8; ++i) {
        f4 v0, v1;
        #pragma unroll
        for (int c = 0; c < 4; ++c) {
          v0[c] = elu1(acc[i][c]     + bb0[c]);
          v1[c] = elu1(acc[i][4 + c] + bb1[c]);
        }
        *(f4*)&sH[(ty + 16*i) * HS + c0]     = v0;
        *(f4*)&sH[(ty + 16*i) * HS + c0 + 4] = v1;
      }
      const f4* gw = (const f4*)(W3 + (size_t)f * H_ * H_);
      f4* sWv = (f4*)sW;
      #pragma unroll
      for (int rr = 0; rr < 16; ++rr) sWv[tid + 256*rr] = gw[tid + 256*rr];
    }
    __syncthreads();
    // ---- GEMM2 (h2*W3 + b3, elu)
    gemm_tile(acc, sH, sW, ty, c0);
    __syncthreads();
    {
      const f4 bb0 = *(const f4*)(b3 + (size_t)f * H_ + c0);
      const f4 bb1 = *(const f4*)(b3 + (size_t)f * H_ + c0 + 4);
      #pragma unroll
      for (int i = 0; i < 8; ++i) {
        f4 v0, v1;
        #pragma unroll
        for (int c = 0; c < 4; ++c) {
          v0[c] = elu1(acc[i][c]     + bb0[c]);
          v1[c] = elu1(acc[i][4 + c] + bb1[c]);
        }
        *(f4*)&sH[(ty + 16*i) * HS + c0]     = v0;
        *(f4*)&sH[(ty + 16*i) * HS + c0 + 4] = v1;
      }
      const f4* gw = (const f4*)(W4 + (size_t)f * H_ * H_);
      f4* sWv = (f4*)sW;
      #pragma unroll
      for (int rr = 0; rr < 16; ++rr) sWv[tid + 256*rr] = gw[tid + 256*rr];
    }
    __syncthreads();
    // ---- GEMM3 (h3*W4 + b4, NO elu) -> bb stays in registers
    gemm_tile(acc, sH, sW, ty, c0);
    // ---- epilogue: backbone accumulation + folded head
    {
      const f4 b40 = *(const f4*)(b4 + (size_t)f * H_ + c0);
      const f4 b41 = *(const f4*)(b4 + (size_t)f * H_ + c0 + 4);
      const f4 wv00 = *(const f4*)(wv + (size_t)(f*2 + 0) * H_ + c0);
      const f4 wv01 = *(const f4*)(wv + (size_t)(f*2 + 0) * H_ + c0 + 4);
      const f4 wv10 = *(const f4*)(wv + (size_t)(f*2 + 1) * H_ + c0);
      const f4 wv11 = *(const f4*)(wv + (size_t)(f*2 + 1) * H_ + c0 + 4);
      const float cb0 = cb[f*2 + 0], cb1 = cb[f*2 + 1];
      #pragma unroll
      for (int i = 0; i < 8; ++i) {
        float vv[8];
        #pragma unroll
        for (int c = 0; c < 4; ++c) {
          vv[c]     = acc[i][c]     + b40[c];
          vv[4 + c] = acc[i][4 + c] + b41[c];
        }
        #pragma unroll
        for (int j = 0; j < 8; ++j) bbsum[i][j] += vv[j];
        const int t = ta[i];
        const f4 wa = t ? wv10 : wv00;
        const f4 wb = t ? wv11 : wv01;
        float s = vv[0]*wa[0] + vv[1]*wa[1] + vv[2]*wa[2] + vv[3]*wa[3]
                + vv[4]*wb[0] + vv[5]*wb[1] + vv[6]*wb[2] + vv[7]*wb[3];
        if (tx == 0) s += t ? cb1 : cb0;
        ysum[i] += s;
      }
    }
  }

  // ---- backbone_sum: cross-group reduction via device-scope atomics
  #pragma unroll
  for (int i = 0; i < 8; ++i) {
    int row = r0 + ty + 16*i;
    #pragma unroll
    for (int j = 0; j < 8; ++j)
      atomicAdd(&out[(size_t)row * H_ + c0 + j], bbsum[i][j]);
  }
  // ---- sum_out: reduce ysum across the 16 tx lanes, then atomic across groups
  #pragma unroll
  for (int i = 0; i < 8; ++i) sY[(ty + 16*i) * 16 + tx] = ysum[i];
  __syncthreads();
  if (tid < TB) {
    float s = 0.f;
    #pragma unroll
    for (int t = 0; t < 16; ++t) s += sY[tid * 16 + t];
    atomicAdd(&out[(size_t)B_ * H_ + r0 + tid], s);
  }
}

extern "C" void kernel_launch(void* const* d_in, const int* in_sizes, int n_in,
                              void* d_out, int out_size, void* d_ws, size_t ws_size,
                              hipStream_t stream) {
  const float* x   = (const float*)d_in[0];
  const int*   aa  = (const int*)d_in[1];
  const float* W1  = (const float*)d_in[2];
  const float* b1  = (const float*)d_in[3];
  const float* W2  = (const float*)d_in[4];
  const float* b2  = (const float*)d_in[5];
  const float* W3  = (const float*)d_in[6];
  const float* b3  = (const float*)d_in[7];
  const float* W4  = (const float*)d_in[8];
  const float* b4  = (const float*)d_in[9];
  const float* Wh1 = (const float*)d_in[10];
  const float* bh1 = (const float*)d_in[11];
  const float* Wh2 = (const float*)d_in[12];
  const float* bh2 = (const float*)d_in[13];
  float* out = (float*)d_out;
  float* wv = (float*)d_ws;                 // F*T*H floats
  float* cb = wv + F_ * T_ * H_;            // F*T floats

  hipMemsetAsync(d_out, 0, (size_t)out_size * sizeof(float), stream);
  head_fold<<<dim3(F_ * T_), dim3(64), 0, stream>>>(Wh1, bh1, Wh2, bh2, wv, cb);
  nam_main<<<dim3(B_ / TB, NG), dim3(256), 0, stream>>>(
      x, aa, W1, b1, W2, b2, W3, b3, W4, b4, wv, cb, out);
}

// Round 2
// 324.575 us; speedup vs baseline: 2.7042x; 2.7042x over previous
//
#include <hip/hip_runtime.h>
#include <hip/hip_bf16.h>
#include <math.h>

#define B_  4096
#define F_  100
#define H_  128
#define H2_ 64
#define NG  16     // feature groups (grid.y)

typedef float    f32x4  __attribute__((ext_vector_type(4)));
typedef __bf16   bf16x8 __attribute__((ext_vector_type(8)));
typedef __bf16   bf16x2 __attribute__((ext_vector_type(2)));
typedef unsigned int uint4v __attribute__((ext_vector_type(4)));

__device__ __forceinline__ float el(float v) { return v > 0.f ? v : __expf(v) - 1.f; }

__device__ __forceinline__ unsigned pkpair(float lo, float hi) {
  bf16x2 t; t[0] = (__bf16)lo; t[1] = (__bf16)hi;
  return __builtin_bit_cast(unsigned, t);
}

// ---- head fold: wv[f,t,h] = sum_m Wh1[f,t,h,m]*Wh2[f,t,m]; cb = bh1.Wh2 + bh2 (unchanged, passing)
__global__ void head_fold(const float* __restrict__ Wh1, const float* __restrict__ bh1,
                          const float* __restrict__ Wh2, const float* __restrict__ bh2,
                          float* __restrict__ wv, float* __restrict__ cb) {
  int bid = blockIdx.x;          // f*T + t, 0..199
  int l = threadIdx.x;           // 0..63
  __shared__ __align__(16) float w2s[H2_];
  w2s[l] = Wh2[bid * H2_ + l];
  __syncthreads();
  const float* base = Wh1 + (size_t)bid * H_ * H2_;
  for (int h = l; h < H_; h += 64) {
    float s = 0.f;
    const f32x4* rw = (const f32x4*)(base + (size_t)h * H2_);
    #pragma unroll
    for (int m4 = 0; m4 < H2_ / 4; ++m4) {
      f32x4 av = rw[m4];
      f32x4 bv = ((const f32x4*)w2s)[m4];
      s += av[0]*bv[0] + av[1]*bv[1] + av[2]*bv[2] + av[3]*bv[3];
    }
    wv[bid * H_ + h] = s;
  }
  float p = bh1[bid * H2_ + l] * w2s[l];
  #pragma unroll
  for (int off = 32; off > 0; off >>= 1) p += __shfl_xor(p, off);
  if (l == 0) cb[bid] = p + bh2[bid];
}

// ---- weight prep: W_l[f] fp32 [k][n] -> bf16 wT[n][k], XOR-swizzled in 16B blocks.
// Output byte layout per (f,layer): elem block (n, c): 8 bf16 (k = 8c..8c+7) stored at
// byte ( n*256 + c*16 ) ^ ((n&7)<<4).  Main kernel stages this linearly and reads with same XOR.
__global__ __launch_bounds__(256) void wprep(const float* __restrict__ W2,
                                             const float* __restrict__ W3,
                                             const float* __restrict__ W4,
                                             __bf16* __restrict__ wb) {
  __shared__ float tile[128 * 132];
  const int bidx = blockIdx.x;          // f*3 + layer
  const int f = bidx / 3, ly = bidx % 3;
  const float* src = (ly == 0 ? W2 : (ly == 1 ? W3 : W4)) + (size_t)f * (H_ * H_);
  const int tid = threadIdx.x;
  #pragma unroll
  for (int r = 0; r < 16; ++r) {
    int i4 = tid + 256 * r;             // f32x4 index 0..4095
    int k = i4 >> 5, n0 = (i4 & 31) << 2;
    *(f32x4*)&tile[k * 132 + n0] = *(const f32x4*)(src + ((size_t)i4 << 2));
  }
  __syncthreads();
  __bf16* wo = wb + (size_t)bidx * (H_ * H_);
  #pragma unroll
  for (int wq = 0; wq < 8; ++wq) {
    int idx = tid + 256 * wq;           // 0..2047
    int n = idx >> 4, c = idx & 15;
    bf16x8 o;
    #pragma unroll
    for (int j = 0; j < 8; ++j) o[j] = (__bf16)tile[(8 * c + j) * 132 + n];
    int boff = (n << 8) + (c << 4);
    boff ^= (n & 7) << 4;
    *(bf16x8*)((char*)wo + boff) = o;
  }
}

// A-fragment read (wT in LDS, swizzled): lane row n = mt*16+lc, k = ks*32+8g..+7 contiguous.
__device__ __forceinline__ bf16x8 lda(const __bf16* buf, int mt, int ks, int lc, int g) {
  int rown = mt * 16 + lc;
  int boff = (rown << 8) + (ks << 6) + (g << 4);
  boff ^= (rown & 7) << 4;
  return *(const bf16x8*)((const char*)buf + boff);
}

// B-fragment via intra-lane-class exchange of previous layer's packed output.
// Consumer lane (g=l>>4) elem e: k = ks*32+8g+e comes from producer lane (l&15)+16*(2(g&1)+(e>>2)),
// tile mt' = 2ks + (g>>1), reg r = e&3.  pk words: [0]=(r1,r0), [1]=(r3,r2).
__device__ __forceinline__ bf16x8 exch(const unsigned (&pks)[8][2], int ks, int s0l, bool hi5) {
  unsigned a0 = __shfl(pks[2*ks][0],   s0l,      64);
  unsigned a1 = __shfl(pks[2*ks][1],   s0l,      64);
  unsigned b0 = __shfl(pks[2*ks+1][0], s0l,      64);
  unsigned b1 = __shfl(pks[2*ks+1][1], s0l,      64);
  unsigned c0 = __shfl(pks[2*ks][0],   s0l + 16, 64);
  unsigned c1 = __shfl(pks[2*ks][1],   s0l + 16, 64);
  unsigned d0 = __shfl(pks[2*ks+1][0], s0l + 16, 64);
  unsigned d1 = __shfl(pks[2*ks+1][1], s0l + 16, 64);
  uint4v u;
  u[0] = hi5 ? b0 : a0;  u[1] = hi5 ? b1 : a1;
  u[2] = hi5 ? d0 : c0;  u[3] = hi5 ? d1 : c1;
  return __builtin_bit_cast(bf16x8, u);
}

#define PHASE_SYNC() do {                                                   \
    asm volatile("s_waitcnt lgkmcnt(0)" ::: "memory");                      \
    __builtin_amdgcn_s_barrier();                                           \
    if (item + 2 < nitems) {                                                \
      stage(item + 2);                                                      \
      asm volatile("s_waitcnt vmcnt(4)" ::: "memory");                      \
    } else {                                                                \
      asm volatile("s_waitcnt vmcnt(0)" ::: "memory");                      \
    }                                                                       \
    __builtin_amdgcn_s_barrier();                                           \
    ++item;                                                                 \
  } while (0)

__global__ __launch_bounds__(512, 2) void nam_mfma(
    const float* __restrict__ x,  const int* __restrict__ a,
    const float* __restrict__ W1, const float* __restrict__ b1,
    const float* __restrict__ b2, const float* __restrict__ b3, const float* __restrict__ b4,
    const float* __restrict__ wv, const float* __restrict__ cb,
    const __bf16* __restrict__ wb, float* __restrict__ out) {
  __shared__ __align__(1024) __bf16 wlds[2][H_ * H_];   // 2 x 32KB double buffer

  const int tid = threadIdx.x;
  const int l  = tid & 63;
  const int lc = l & 15, g = l >> 4;
  const int rw = blockIdx.x * 256 + (tid >> 6) * 32;    // wave's 32-row base
  const int by = blockIdx.y;
  const int f0 = (by * F_) / NG, f1 = ((by + 1) * F_) / NG;
  const int nitems = 3 * (f1 - f0);

  const int row0 = rw + lc, row1 = rw + 16 + lc;
  const int ta0 = a[row0], ta1 = a[row1];
  const int s0l = lc + ((l & 16) << 1);
  const bool hi5 = (l & 32) != 0;

  f32x4 acc[8][2], bbsum[8][2];
  unsigned pk[2][8][2];
  const f32x4 z = {0.f, 0.f, 0.f, 0.f};
  #pragma unroll
  for (int mt = 0; mt < 8; ++mt) { bbsum[mt][0] = z; bbsum[mt][1] = z; }
  float ysum0 = 0.f, ysum1 = 0.f;

  auto stage = [&](int it) {
    const char* gsrc = (const char*)(wb + (size_t)(f0 * 3 + it) * (H_ * H_));
    char* ldst = (char*)&wlds[it & 1][0];
    #pragma unroll
    for (int r = 0; r < 4; ++r) {
      int off = (tid + 512 * r) * 16;
      __builtin_amdgcn_global_load_lds(
          (const __attribute__((address_space(1))) void*)(gsrc + off),
          (__attribute__((address_space(3))) void*)(ldst + off), 16, 0, 0);
    }
  };

  stage(0); stage(1);
  asm volatile("s_waitcnt vmcnt(4)" ::: "memory");
  __builtin_amdgcn_s_barrier();

  int item = 0;
  for (int fi = f0; fi < f1; ++fi) {
    // ================= phase 0: GEMM2 (h2 = elu(h1 W2 + b2)); h1 built on the fly =========
    {
      const __bf16* buf = wlds[item & 1];
      #pragma unroll
      for (int mt = 0; mt < 8; ++mt) { acc[mt][0] = z; acc[mt][1] = z; }
      const float* w1p = W1 + (size_t)fi * H_;
      const float* b1p = b1 + (size_t)fi * H_;
      float xs0 = x[(size_t)row0 * F_ + fi];
      float xs1 = x[(size_t)row1 * F_ + fi];
      #pragma unroll
      for (int ks = 0; ks < 4; ++ks) {
        int k0 = ks * 32 + 8 * g;
        f32x4 wa  = *(const f32x4*)(w1p + k0);
        f32x4 wb2 = *(const f32x4*)(w1p + k0 + 4);
        f32x4 ba  = *(const f32x4*)(b1p + k0);
        f32x4 bb2 = *(const f32x4*)(b1p + k0 + 4);
        bf16x8 bf0, bf1;
        #pragma unroll
        for (int e = 0; e < 4; ++e) {
          bf0[e]     = (__bf16)el(xs0 * wa[e]  + ba[e]);
          bf0[e + 4] = (__bf16)el(xs0 * wb2[e] + bb2[e]);
          bf1[e]     = (__bf16)el(xs1 * wa[e]  + ba[e]);
          bf1[e + 4] = (__bf16)el(xs1 * wb2[e] + bb2[e]);
        }
        #pragma unroll
        for (int mt = 0; mt < 8; ++mt) {
          bf16x8 av = lda(buf, mt, ks, lc, g);
          acc[mt][0] = __builtin_amdgcn_mfma_f32_16x16x32_bf16(av, bf0, acc[mt][0], 0, 0, 0);
          acc[mt][1] = __builtin_amdgcn_mfma_f32_16x16x32_bf16(av, bf1, acc[mt][1], 0, 0, 0);
        }
      }
      const float* bp = b2 + (size_t)fi * H_;
      #pragma unroll
      for (int mt = 0; mt < 8; ++mt) {
        f32x4 bia = *(const f32x4*)(bp + mt * 16 + 4 * g);
        #pragma unroll
        for (int nt = 0; nt < 2; ++nt) {
          f32x4 t = acc[mt][nt];
          float t0 = el(t[0] + bia[0]), t1 = el(t[1] + bia[1]);
          float t2 = el(t[2] + bia[2]), t3 = el(t[3] + bia[3]);
          pk[nt][mt][0] = pkpair(t0, t1);
          pk[nt][mt][1] = pkpair(t2, t3);
        }
      }
    }
    PHASE_SYNC();
    // ================= phase 1: GEMM3 (h3 = elu(h2 W3 + b3)) ==============================
    {
      const __bf16* buf = wlds[item & 1];
      #pragma unroll
      for (int mt = 0; mt < 8; ++mt) { acc[mt][0] = z; acc[mt][1] = z; }
      #pragma unroll
      for (int ks = 0; ks < 4; ++ks) {
        bf16x8 bf0 = exch(pk[0], ks, s0l, hi5);
        bf16x8 bf1 = exch(pk[1], ks, s0l, hi5);
        #pragma unroll
        for (int mt = 0; mt < 8; ++mt) {
          bf16x8 av = lda(buf, mt, ks, lc, g);
          acc[mt][0] = __builtin_amdgcn_mfma_f32_16x16x32_bf16(av, bf0, acc[mt][0], 0, 0, 0);
          acc[mt][1] = __builtin_amdgcn_mfma_f32_16x16x32_bf16(av, bf1, acc[mt][1], 0, 0, 0);
        }
      }
      const float* bp = b3 + (size_t)fi * H_;
      #pragma unroll
      for (int mt = 0; mt < 8; ++mt) {
        f32x4 bia = *(const f32x4*)(bp + mt * 16 + 4 * g);
        #pragma unroll
        for (int nt = 0; nt < 2; ++nt) {
          f32x4 t = acc[mt][nt];
          float t0 = el(t[0] + bia[0]), t1 = el(t[1] + bia[1]);
          float t2 = el(t[2] + bia[2]), t3 = el(t[3] + bia[3]);
          pk[nt][mt][0] = pkpair(t0, t1);
          pk[nt][mt][1] = pkpair(t2, t3);
        }
      }
    }
    PHASE_SYNC();
    // ================= phase 2: GEMM4 (bb = h3 W4 + b4, no elu) + heads ===================
    {
      const __bf16* buf = wlds[item & 1];
      #pragma unroll
      for (int mt = 0; mt < 8; ++mt) { acc[mt][0] = z; acc[mt][1] = z; }
      #pragma unroll
      for (int ks = 0; ks < 4; ++ks) {
        bf16x8 bf0 = exch(pk[0], ks, s0l, hi5);
        bf16x8 bf1 = exch(pk[1], ks, s0l, hi5);
        #pragma unroll
        for (int mt = 0; mt < 8; ++mt) {
          bf16x8 av = lda(buf, mt, ks, lc, g);
          acc[mt][0] = __builtin_amdgcn_mfma_f32_16x16x32_bf16(av, bf0, acc[mt][0], 0, 0, 0);
          acc[mt][1] = __builtin_amdgcn_mfma_f32_16x16x32_bf16(av, bf1, acc[mt][1], 0, 0, 0);
        }
      }
      const float* b4p = b4 + (size_t)fi * H_;
      const float* wv0 = wv + (size_t)(fi * 2 + ta0) * H_;
      const float* wv1 = wv + (size_t)(fi * 2 + ta1) * H_;
      float yd0 = 0.f, yd1 = 0.f;
      #pragma unroll
      for (int mt = 0; mt < 8; ++mt) {
        int n = mt * 16 + 4 * g;
        f32x4 bia = *(const f32x4*)(b4p + n);
        f32x4 v0 = acc[mt][0] + bia;
        f32x4 v1 = acc[mt][1] + bia;
        bbsum[mt][0] += v0;
        bbsum[mt][1] += v1;
        f32x4 wa = *(const f32x4*)(wv0 + n);
        f32x4 wc = *(const f32x4*)(wv1 + n);
        yd0 += v0[0]*wa[0] + v0[1]*wa[1] + v0[2]*wa[2] + v0[3]*wa[3];
        yd1 += v1[0]*wc[0] + v1[1]*wc[1] + v1[2]*wc[2] + v1[3]*wc[3];
      }
      ysum0 += yd0 + (g == 0 ? cb[fi * 2 + ta0] : 0.f);
      ysum1 += yd1 + (g == 0 ? cb[fi * 2 + ta1] : 0.f);
    }
    PHASE_SYNC();
  }

  // ---- backbone_sum atomics (cross-feature-group reduction)
  #pragma unroll
  for (int mt = 0; mt < 8; ++mt) {
    int n = mt * 16 + 4 * g;
    float* p0 = out + (size_t)row0 * H_ + n;
    float* p1 = out + (size_t)row1 * H_ + n;
    #pragma unroll
    for (int r = 0; r < 4; ++r) {
      atomicAdd(p0 + r, bbsum[mt][0][r]);
      atomicAdd(p1 + r, bbsum[mt][1][r]);
    }
  }
  // ---- sum_out: reduce over the 4 lanes of each row-class, then atomic
  float y0 = ysum0 + __shfl_xor(ysum0, 16, 64); y0 += __shfl_xor(y0, 32, 64);
  float y1 = ysum1 + __shfl_xor(ysum1, 16, 64); y1 += __shfl_xor(y1, 32, 64);
  if (g == 0) {
    atomicAdd(out + (size_t)B_ * H_ + row0, y0);
    atomicAdd(out + (size_t)B_ * H_ + row1, y1);
  }
}

extern "C" void kernel_launch(void* const* d_in, const int* in_sizes, int n_in,
                              void* d_out, int out_size, void* d_ws, size_t ws_size,
                              hipStream_t stream) {
  const float* x   = (const float*)d_in[0];
  const int*   aa  = (const int*)d_in[1];
  const float* W1  = (const float*)d_in[2];
  const float* b1  = (const float*)d_in[3];
  const float* W2  = (const float*)d_in[4];
  const float* b2  = (const float*)d_in[5];
  const float* W3  = (const float*)d_in[6];
  const float* b3  = (const float*)d_in[7];
  const float* W4  = (const float*)d_in[8];
  const float* b4  = (const float*)d_in[9];
  const float* Wh1 = (const float*)d_in[10];
  const float* bh1 = (const float*)d_in[11];
  const float* Wh2 = (const float*)d_in[12];
  const float* bh2 = (const float*)d_in[13];
  float* out = (float*)d_out;

  float*  wv  = (float*)d_ws;                           // 200*128 f32
  float*  cbp = (float*)((char*)d_ws + 102400);         // 200 f32
  __bf16* wbp = (__bf16*)((char*)d_ws + 103424);        // 300*16384 bf16 (~9.8 MB)

  hipMemsetAsync(d_out, 0, (size_t)out_size * sizeof(float), stream);
  head_fold<<<dim3(F_ * 2), dim3(64), 0, stream>>>(Wh1, bh1, Wh2, bh2, wv, cbp);
  wprep<<<dim3(F_ * 3), dim3(256), 0, stream>>>(W2, W3, W4, wbp);
  nam_mfma<<<dim3(B_ / 256, NG), dim3(512), 0, stream>>>(
      x, aa, W1, b1, b2, b3, b4, wv, cbp, wbp, out);
}

// Round 3
// 229.538 us; speedup vs baseline: 3.8238x; 1.4140x over previous
//
#include <hip/hip_runtime.h>
#include <hip/hip_bf16.h>
#include <math.h>

#define B_  4096
#define F_  100
#define H_  128
#define H2_ 64
#define NG  16     // feature groups (grid.y)

typedef float    f32x4  __attribute__((ext_vector_type(4)));
typedef __bf16   bf16x8 __attribute__((ext_vector_type(8)));
typedef __bf16   bf16x2 __attribute__((ext_vector_type(2)));
typedef unsigned int uint4v __attribute__((ext_vector_type(4)));

__device__ __forceinline__ float el(float v) { return v > 0.f ? v : __expf(v) - 1.f; }

__device__ __forceinline__ unsigned pkpair(float lo, float hi) {
  bf16x2 t; t[0] = (__bf16)lo; t[1] = (__bf16)hi;
  return __builtin_bit_cast(unsigned, t);
}

// ================= fused prep: wprep(300) + head_fold(200) + x-transpose(16) ==============
// wb layout per (f,layer): 8-bf16 block (n, c) [k=8c..8c+7] at byte (n*256 + c*16) ^ ((n&7)<<4)
__global__ __launch_bounds__(256) void prep(
    const float* __restrict__ W2, const float* __restrict__ W3, const float* __restrict__ W4,
    const float* __restrict__ Wh1, const float* __restrict__ bh1,
    const float* __restrict__ Wh2, const float* __restrict__ bh2,
    const float* __restrict__ x,
    __bf16* __restrict__ wb, float* __restrict__ wv, float* __restrict__ cb,
    float* __restrict__ xT) {
  const int bid = blockIdx.x;
  const int tid = threadIdx.x;
  if (bid < 300) {
    // ---- weight transpose+pack (as R2 wprep, proven)
    __shared__ float tile[128 * 132];
    const int f = bid / 3, ly = bid % 3;
    const float* src = (ly == 0 ? W2 : (ly == 1 ? W3 : W4)) + (size_t)f * (H_ * H_);
    #pragma unroll
    for (int r = 0; r < 16; ++r) {
      int i4 = tid + 256 * r;
      int k = i4 >> 5, n0 = (i4 & 31) << 2;
      *(f32x4*)&tile[k * 132 + n0] = *(const f32x4*)(src + ((size_t)i4 << 2));
    }
    __syncthreads();
    __bf16* wo = wb + (size_t)bid * (H_ * H_);
    #pragma unroll
    for (int wq = 0; wq < 8; ++wq) {
      int idx = tid + 256 * wq;
      int n = idx >> 4, c = idx & 15;
      bf16x8 o;
      #pragma unroll
      for (int j = 0; j < 8; ++j) o[j] = (__bf16)tile[(8 * c + j) * 132 + n];
      int boff = (n << 8) + (c << 4);
      boff ^= (n & 7) << 4;
      *(bf16x8*)((char*)wo + boff) = o;
    }
  } else if (bid < 500) {
    // ---- head fold: wv[f,t,h] = sum_m Wh1*Wh2 ; cb = bh1.Wh2 + bh2
    const int hb = bid - 300;          // f*2 + t
    __shared__ __align__(16) float w2s[H2_];
    if (tid < 64) w2s[tid] = Wh2[hb * H2_ + tid];
    __syncthreads();
    const int h = tid >> 1, half = tid & 1;
    const f32x4* rw = (const f32x4*)(Wh1 + ((size_t)hb * H_ + h) * H2_ + half * 32);
    const f32x4* bvp = (const f32x4*)&w2s[half * 32];
    float s = 0.f;
    #pragma unroll
    for (int m4 = 0; m4 < 8; ++m4) {
      f32x4 av = rw[m4], bv = bvp[m4];
      s += av[0]*bv[0] + av[1]*bv[1] + av[2]*bv[2] + av[3]*bv[3];
    }
    s += __shfl_xor(s, 1);
    if (!half) wv[hb * H_ + h] = s;
    if (tid < 64) {
      float p = bh1[hb * H2_ + tid] * w2s[tid];
      #pragma unroll
      for (int off = 32; off > 0; off >>= 1) p += __shfl_xor(p, off);
      if (tid == 0) cb[hb] = p + bh2[hb];
    }
  } else {
    // ---- x transpose: xT[f][b] = x[b][f]
    const int r = (bid - 500) * 256 + tid;
    const f32x4* src = (const f32x4*)(x + (size_t)r * F_);
    #pragma unroll 5
    for (int j4 = 0; j4 < F_ / 4; ++j4) {
      f32x4 v = src[j4];
      #pragma unroll
      for (int c = 0; c < 4; ++c) xT[(size_t)(j4 * 4 + c) * B_ + r] = v[c];
    }
  }
}

// A-fragment read (wT in LDS, swizzled): lane row n = mt*16+lc, k = ks*32+8g..+7 contiguous.
__device__ __forceinline__ bf16x8 lda(const __bf16* buf, int mt, int ks, int lc, int g) {
  int rown = mt * 16 + lc;
  int boff = (rown << 8) + (ks << 6) + (g << 4);
  boff ^= (rown & 7) << 4;
  return *(const bf16x8*)((const char*)buf + boff);
}

// B-fragment via intra-lane-class exchange of previous layer's packed output.
__device__ __forceinline__ bf16x8 exch(const unsigned (&pks)[8][2], int ks, int s0l, bool hi5) {
  unsigned a0 = __shfl(pks[2*ks][0],   s0l,      64);
  unsigned a1 = __shfl(pks[2*ks][1],   s0l,      64);
  unsigned b0 = __shfl(pks[2*ks+1][0], s0l,      64);
  unsigned b1 = __shfl(pks[2*ks+1][1], s0l,      64);
  unsigned c0 = __shfl(pks[2*ks][0],   s0l + 16, 64);
  unsigned c1 = __shfl(pks[2*ks][1],   s0l + 16, 64);
  unsigned d0 = __shfl(pks[2*ks+1][0], s0l + 16, 64);
  unsigned d1 = __shfl(pks[2*ks+1][1], s0l + 16, 64);
  uint4v u;
  u[0] = hi5 ? b0 : a0;  u[1] = hi5 ? b1 : a1;
  u[2] = hi5 ? d0 : c0;  u[3] = hi5 ? d1 : c1;
  return __builtin_bit_cast(bf16x8, u);
}

#define PHASE_SYNC() do {                                                   \
    asm volatile("s_waitcnt lgkmcnt(0)" ::: "memory");                      \
    __builtin_amdgcn_s_barrier();                                           \
    if (item + 2 < nitems) {                                                \
      stage(item + 2);                                                      \
      asm volatile("s_waitcnt vmcnt(8)" ::: "memory");                      \
    } else {                                                                \
      asm volatile("s_waitcnt vmcnt(0)" ::: "memory");                      \
    }                                                                       \
    __builtin_amdgcn_s_barrier();                                           \
    ++item;                                                                 \
  } while (0)

__global__ __launch_bounds__(256, 2) void nam_mfma(
    const float* __restrict__ xT, const int* __restrict__ a,
    const float* __restrict__ W1, const float* __restrict__ b1,
    const float* __restrict__ b2, const float* __restrict__ b3, const float* __restrict__ b4,
    const float* __restrict__ wv, const float* __restrict__ cb,
    const __bf16* __restrict__ wb,
    float* __restrict__ pbb, float* __restrict__ py) {
  __shared__ __align__(1024) __bf16 wlds[2][H_ * H_];   // 2 x 32KB double buffer

  const int tid = threadIdx.x;
  const int l  = tid & 63;
  const int lc = l & 15, g = l >> 4;
  const int rw = blockIdx.x * 128 + (tid >> 6) * 32;    // wave's 32-row base (4 waves)
  const int by = blockIdx.y;
  const int f0 = (by * F_) / NG, f1 = ((by + 1) * F_) / NG;
  const int nitems = 3 * (f1 - f0);

  const int row0 = rw + lc, row1 = rw + 16 + lc;
  const int ta0 = a[row0], ta1 = a[row1];
  const int s0l = lc + ((l & 16) << 1);
  const bool hi5 = (l & 32) != 0;

  f32x4 acc[8][2], bbsum[8][2];
  unsigned pk[2][8][2];
  const f32x4 z = {0.f, 0.f, 0.f, 0.f};
  #pragma unroll
  for (int mt = 0; mt < 8; ++mt) { bbsum[mt][0] = z; bbsum[mt][1] = z; }
  float ysum0 = 0.f, ysum1 = 0.f;

  auto stage = [&](int it) {
    const char* gsrc = (const char*)(wb + (size_t)(f0 * 3 + it) * (H_ * H_));
    char* ldst = (char*)&wlds[it & 1][0];
    #pragma unroll
    for (int r = 0; r < 8; ++r) {
      int off = (tid + 256 * r) * 16;
      __builtin_amdgcn_global_load_lds(
          (const __attribute__((address_space(1))) void*)(gsrc + off),
          (__attribute__((address_space(3))) void*)(ldst + off), 16, 0, 0);
    }
  };

  stage(0); stage(1);
  asm volatile("s_waitcnt vmcnt(8)" ::: "memory");
  __builtin_amdgcn_s_barrier();

  int item = 0;
  for (int fi = f0; fi < f1; ++fi) {
    // ================= phase 0: GEMM2 (h2 = elu(h1 W2 + b2)); h1 built on the fly =========
    {
      const __bf16* buf = wlds[item & 1];
      #pragma unroll
      for (int mt = 0; mt < 8; ++mt) { acc[mt][0] = z; acc[mt][1] = z; }
      const float* w1p = W1 + (size_t)fi * H_;
      const float* b1p = b1 + (size_t)fi * H_;
      float xs0 = xT[(size_t)fi * B_ + row0];
      float xs1 = xT[(size_t)fi * B_ + row1];
      #pragma unroll
      for (int ks = 0; ks < 4; ++ks) {
        int k0 = ks * 32 + 8 * g;
        f32x4 wa  = *(const f32x4*)(w1p + k0);
        f32x4 wb2 = *(const f32x4*)(w1p + k0 + 4);
        f32x4 ba  = *(const f32x4*)(b1p + k0);
        f32x4 bb2 = *(const f32x4*)(b1p + k0 + 4);
        bf16x8 bf0, bf1;
        #pragma unroll
        for (int e = 0; e < 4; ++e) {
          bf0[e]     = (__bf16)el(xs0 * wa[e]  + ba[e]);
          bf0[e + 4] = (__bf16)el(xs0 * wb2[e] + bb2[e]);
          bf1[e]     = (__bf16)el(xs1 * wa[e]  + ba[e]);
          bf1[e + 4] = (__bf16)el(xs1 * wb2[e] + bb2[e]);
        }
        #pragma unroll
        for (int mt = 0; mt < 8; ++mt) {
          bf16x8 av = lda(buf, mt, ks, lc, g);
          acc[mt][0] = __builtin_amdgcn_mfma_f32_16x16x32_bf16(av, bf0, acc[mt][0], 0, 0, 0);
          acc[mt][1] = __builtin_amdgcn_mfma_f32_16x16x32_bf16(av, bf1, acc[mt][1], 0, 0, 0);
        }
      }
      const float* bp = b2 + (size_t)fi * H_;
      #pragma unroll
      for (int mt = 0; mt < 8; ++mt) {
        f32x4 bia = *(const f32x4*)(bp + mt * 16 + 4 * g);
        #pragma unroll
        for (int nt = 0; nt < 2; ++nt) {
          f32x4 t = acc[mt][nt];
          float t0 = el(t[0] + bia[0]), t1 = el(t[1] + bia[1]);
          float t2 = el(t[2] + bia[2]), t3 = el(t[3] + bia[3]);
          pk[nt][mt][0] = pkpair(t0, t1);
          pk[nt][mt][1] = pkpair(t2, t3);
        }
      }
    }
    PHASE_SYNC();
    // ================= phase 1: GEMM3 (h3 = elu(h2 W3 + b3)) ==============================
    {
      const __bf16* buf = wlds[item & 1];
      #pragma unroll
      for (int mt = 0; mt < 8; ++mt) { acc[mt][0] = z; acc[mt][1] = z; }
      #pragma unroll
      for (int ks = 0; ks < 4; ++ks) {
        bf16x8 bf0 = exch(pk[0], ks, s0l, hi5);
        bf16x8 bf1 = exch(pk[1], ks, s0l, hi5);
        #pragma unroll
        for (int mt = 0; mt < 8; ++mt) {
          bf16x8 av = lda(buf, mt, ks, lc, g);
          acc[mt][0] = __builtin_amdgcn_mfma_f32_16x16x32_bf16(av, bf0, acc[mt][0], 0, 0, 0);
          acc[mt][1] = __builtin_amdgcn_mfma_f32_16x16x32_bf16(av, bf1, acc[mt][1], 0, 0, 0);
        }
      }
      const float* bp = b3 + (size_t)fi * H_;
      #pragma unroll
      for (int mt = 0; mt < 8; ++mt) {
        f32x4 bia = *(const f32x4*)(bp + mt * 16 + 4 * g);
        #pragma unroll
        for (int nt = 0; nt < 2; ++nt) {
          f32x4 t = acc[mt][nt];
          float t0 = el(t[0] + bia[0]), t1 = el(t[1] + bia[1]);
          float t2 = el(t[2] + bia[2]), t3 = el(t[3] + bia[3]);
          pk[nt][mt][0] = pkpair(t0, t1);
          pk[nt][mt][1] = pkpair(t2, t3);
        }
      }
    }
    PHASE_SYNC();
    // ================= phase 2: GEMM4 (bb = h3 W4 + b4, no elu) + heads ===================
    {
      const __bf16* buf = wlds[item & 1];
      #pragma unroll
      for (int mt = 0; mt < 8; ++mt) { acc[mt][0] = z; acc[mt][1] = z; }
      #pragma unroll
      for (int ks = 0; ks < 4; ++ks) {
        bf16x8 bf0 = exch(pk[0], ks, s0l, hi5);
        bf16x8 bf1 = exch(pk[1], ks, s0l, hi5);
        #pragma unroll
        for (int mt = 0; mt < 8; ++mt) {
          bf16x8 av = lda(buf, mt, ks, lc, g);
          acc[mt][0] = __builtin_amdgcn_mfma_f32_16x16x32_bf16(av, bf0, acc[mt][0], 0, 0, 0);
          acc[mt][1] = __builtin_amdgcn_mfma_f32_16x16x32_bf16(av, bf1, acc[mt][1], 0, 0, 0);
        }
      }
      const float* b4p = b4 + (size_t)fi * H_;
      const float* wv0 = wv + (size_t)(fi * 2 + ta0) * H_;
      const float* wv1 = wv + (size_t)(fi * 2 + ta1) * H_;
      float yd0 = 0.f, yd1 = 0.f;
      #pragma unroll
      for (int mt = 0; mt < 8; ++mt) {
        int n = mt * 16 + 4 * g;
        f32x4 bia = *(const f32x4*)(b4p + n);
        f32x4 v0 = acc[mt][0] + bia;
        f32x4 v1 = acc[mt][1] + bia;
        bbsum[mt][0] += v0;
        bbsum[mt][1] += v1;
        f32x4 wa = *(const f32x4*)(wv0 + n);
        f32x4 wc = *(const f32x4*)(wv1 + n);
        yd0 += v0[0]*wa[0] + v0[1]*wa[1] + v0[2]*wa[2] + v0[3]*wa[3];
        yd1 += v1[0]*wc[0] + v1[1]*wc[1] + v1[2]*wc[2] + v1[3]*wc[3];
      }
      ysum0 += yd0 + (g == 0 ? cb[fi * 2 + ta0] : 0.f);
      ysum1 += yd1 + (g == 0 ? cb[fi * 2 + ta1] : 0.f);
    }
    PHASE_SYNC();
  }

  // ---- partial stores (no atomics): pbb[by][row][col], py[by][row]
  #pragma unroll
  for (int mt = 0; mt < 8; ++mt) {
    int n = mt * 16 + 4 * g;
    *(f32x4*)(pbb + ((size_t)by * B_ + row0) * H_ + n) = bbsum[mt][0];
    *(f32x4*)(pbb + ((size_t)by * B_ + row1) * H_ + n) = bbsum[mt][1];
  }
  float y0 = ysum0 + __shfl_xor(ysum0, 16, 64); y0 += __shfl_xor(y0, 32, 64);
  float y1 = ysum1 + __shfl_xor(ysum1, 16, 64); y1 += __shfl_xor(y1, 32, 64);
  if (g == 0) {
    py[by * B_ + row0] = y0;
    py[by * B_ + row1] = y1;
  }
}

// ================= final reduction over the NG feature groups =============================
__global__ __launch_bounds__(256) void reduce_out(const float* __restrict__ pbb,
                                                  const float* __restrict__ py,
                                                  float* __restrict__ out) {
  const int idx = blockIdx.x * 256 + threadIdx.x;
  if (idx < B_ * H_) {
    float s = 0.f;
    #pragma unroll
    for (int g = 0; g < NG; ++g) s += pbb[(size_t)g * (B_ * H_) + idx];
    out[idx] = s;
  } else if (idx < B_ * H_ + B_) {
    const int b = idx - B_ * H_;
    float s = 0.f;
    #pragma unroll
    for (int g = 0; g < NG; ++g) s += py[g * B_ + b];
    out[idx] = s;
  }
}

extern "C" void kernel_launch(void* const* d_in, const int* in_sizes, int n_in,
                              void* d_out, int out_size, void* d_ws, size_t ws_size,
                              hipStream_t stream) {
  const float* x   = (const float*)d_in[0];
  const int*   aa  = (const int*)d_in[1];
  const float* W1  = (const float*)d_in[2];
  const float* b1  = (const float*)d_in[3];
  const float* W2  = (const float*)d_in[4];
  const float* b2  = (const float*)d_in[5];
  const float* W3  = (const float*)d_in[6];
  const float* b3  = (const float*)d_in[7];
  const float* W4  = (const float*)d_in[8];
  const float* b4  = (const float*)d_in[9];
  const float* Wh1 = (const float*)d_in[10];
  const float* bh1 = (const float*)d_in[11];
  const float* Wh2 = (const float*)d_in[12];
  const float* bh2 = (const float*)d_in[13];
  float* out = (float*)d_out;

  char* ws = (char*)d_ws;
  float*  wv  = (float*)(ws + 0);              // 102,400 B
  float*  cbp = (float*)(ws + 102400);         // 800 B
  __bf16* wbp = (__bf16*)(ws + 103424);        // 9,830,400 B
  float*  xT  = (float*)(ws + 9933824);        // 1,638,400 B
  float*  py  = (float*)(ws + 11572224);       // 262,144 B
  float*  pbb = (float*)(ws + 11834368);       // 33,554,432 B

  prep<<<dim3(516), dim3(256), 0, stream>>>(W2, W3, W4, Wh1, bh1, Wh2, bh2, x,
                                            wbp, wv, cbp, xT);
  nam_mfma<<<dim3(B_ / 128, NG), dim3(256), 0, stream>>>(
      xT, aa, W1, b1, b2, b3, b4, wv, cbp, wbp, pbb, py);
  reduce_out<<<dim3((B_ * H_ + B_ + 255) / 256), dim3(256), 0, stream>>>(pbb, py, out);
}